// Round 1
// baseline (207.709 us; speedup 1.0000x reference)
//
#include <hip/hip_runtime.h>
#include <math.h>

// SNN event model: causal conv (K=8) + LIF scan + outputs (I, z, s, logits).
// Layout: x (32,1,8192) f32, conv_w (64,1,8) f32, raw_tau (64,) f32.
// out = [I (32*64*8192), z (same), s (same), logits (32*8192)] fp32.
//
// Parallelization: time split into NCH chunks per (b) with warm-up W; each
// block = 1 wave (64 lanes = 64 features) handles one (b, chunk).
// fp64 recurrence (compute is free; we are write-BW bound at ~202 MB).

#define LL 8192
#define BB 32
#define FF 64
#define KK 8
#define CHUNK 128
#define NCH 64              // LL / CHUNK
#define WARM 96
#define NX (WARM + 7 + CHUNK)  // 231
#define TS 32               // flush tile (timesteps buffered in LDS)
#define NT (CHUNK / TS)

__global__ __launch_bounds__(64) void snn_kernel(
    const float* __restrict__ x, const float* __restrict__ conv_w,
    const float* __restrict__ raw_tau, float* __restrict__ out)
{
    __shared__ double x_lds[NX + 1];
    __shared__ float I_tile[FF][TS + 1];   // stride 33: column writes conflict-free
    __shared__ float z_tile[FF][TS + 1];

    const int f  = threadIdx.x;            // lane = feature
    const int b  = blockIdx.y;
    const int c  = blockIdx.x;
    const int t0 = c * CHUNK;
    const int g0 = t0 - WARM - 7;          // global time of x_lds[0]

    // ---- per-feature weights: unit-norm filter + alpha ----
    double wd[KK];
    double ss = 0.0;
    #pragma unroll
    for (int k = 0; k < KK; ++k) {
        double wv = (double)conv_w[f * KK + k];
        wd[k] = wv;
        ss += wv * wv;
    }
    double nrm = sqrt(ss);
    if (nrm < 1e-8) nrm = 1e-8;
    double invn = 1.0 / nrm;
    #pragma unroll
    for (int k = 0; k < KK; ++k) wd[k] *= invn;

    double rt    = (double)raw_tau[f];
    double tau   = log1p(exp(rt)) + 1e-4;  // softplus + eps
    double alpha = exp(-1.0 / tau);
    double oma   = 1.0 - alpha;

    // ---- stage 20*x into LDS (zero pad for t<0) ----
    for (int i = f; i < NX; i += 64) {
        int g = g0 + i;
        x_lds[i] = (g >= 0) ? (double)(20.0f * x[(size_t)b * LL + g]) : 0.0;
    }
    __syncthreads();

    float* outI  = out;
    float* outZ  = out + (size_t)BB * FF * LL;
    float* outS  = out + (size_t)2 * BB * FF * LL;
    float* outLg = out + (size_t)3 * BB * FF * LL;

    double v = 0.0;

    // ---- warm-up (chunk 0: x is all zero-pad early, v stays 0 — harmless) ----
    #pragma unroll 8
    for (int s = 0; s < WARM; ++s) {
        double acc = 0.0;
        #pragma unroll
        for (int k = 0; k < KK; ++k) acc = fma(wd[k], x_lds[s + k], acc);
        double vp = fma(alpha, v, oma * acc);
        v = (vp >= 0.25) ? 0.0 : vp;
    }

    // ---- main chunk: compute + tile in LDS, flush coalesced ----
    for (int tile = 0; tile < NT; ++tile) {
        #pragma unroll
        for (int j = 0; j < TS; ++j) {
            int s = WARM + tile * TS + j;
            double acc = 0.0;
            #pragma unroll
            for (int k = 0; k < KK; ++k) acc = fma(wd[k], x_lds[s + k], acc);
            double vp = fma(alpha, v, oma * acc);
            double z  = 15.0 * (vp - 0.25);
            I_tile[f][j] = (float)acc;
            z_tile[f][j] = (float)z;
            v = (vp >= 0.25) ? 0.0 : vp;
        }
        __syncthreads();

        const int gt = t0 + tile * TS;
        {
            // 64 lanes -> 8 rows x 8 float4-columns per iteration; coalesced stores.
            int r = f >> 3;          // row within group
            int q = (f & 7) * 4;     // time offset (16B aligned)
            #pragma unroll
            for (int it = 0; it < 8; ++it) {
                int fr = it * 8 + r;
                size_t base = ((size_t)b * FF + fr) * LL + gt + q;
                float4 vi = make_float4(I_tile[fr][q], I_tile[fr][q + 1],
                                        I_tile[fr][q + 2], I_tile[fr][q + 3]);
                float4 vz = make_float4(z_tile[fr][q], z_tile[fr][q + 1],
                                        z_tile[fr][q + 2], z_tile[fr][q + 3]);
                float4 vs = make_float4(vz.x >= 0.f ? 1.f : 0.f,
                                        vz.y >= 0.f ? 1.f : 0.f,
                                        vz.z >= 0.f ? 1.f : 0.f,
                                        vz.w >= 0.f ? 1.f : 0.f);
                *reinterpret_cast<float4*>(outI + base) = vi;
                *reinterpret_cast<float4*>(outZ + base) = vz;
                *reinterpret_cast<float4*>(outS + base) = vs;
            }
            if (f < TS) {   // logits: max over features at time gt+f
                float m = z_tile[0][f];
                #pragma unroll
                for (int ff = 1; ff < FF; ++ff) m = fmaxf(m, z_tile[ff][f]);
                outLg[(size_t)b * LL + gt + f] = m;
            }
        }
        __syncthreads();
    }
}

extern "C" void kernel_launch(void* const* d_in, const int* in_sizes, int n_in,
                              void* d_out, int out_size, void* d_ws, size_t ws_size,
                              hipStream_t stream) {
    const float* x  = (const float*)d_in[0];
    const float* w  = (const float*)d_in[1];
    const float* rt = (const float*)d_in[2];
    float* out = (float*)d_out;
    dim3 grid(NCH, BB);
    snn_kernel<<<grid, 64, 0, stream>>>(x, w, rt, out);
}